// Round 1
// baseline (7197.070 us; speedup 1.0000x reference)
//
#include <hip/hip_runtime.h>
#include <hip/hip_bf16.h>
#include <math.h>

#define NPTS 16384
#define NE 4
#define NM 2048
#define DD 128    // D3
#define DP 64     // D1
#define NHE 256
#define NHM 256
#define NRES 64
#define NTK 16
#define NEG_INF -3.402823466e38f

// ---------- helpers ----------
__device__ __forceinline__ bool rank_gt(float av, int ai, float bv, int bi) {
  // "ranks higher in top-k": larger value, ties broken by lower index (jax top_k)
  return (av > bv) || (av == bv && ai < bi);
}

__device__ __forceinline__ void topk_insert(float (&tv)[16], int (&ti)[16], float v, int k) {
  if (!rank_gt(v, k, tv[15], ti[15])) return;
  tv[15] = v; ti[15] = k;
#pragma unroll
  for (int j = 15; j > 0; --j) {
    bool sw = rank_gt(tv[j], ti[j], tv[j-1], ti[j-1]);
    if (sw) {
      float a = tv[j]; tv[j] = tv[j-1]; tv[j-1] = a;
      int b = ti[j]; ti[j] = ti[j-1]; ti[j-1] = b;
    }
  }
}

__device__ __forceinline__ void topk_merge_write(float (&tv)[16], int (&ti)[16],
                                                 float* attnW, int* attnI,
                                                 size_t off, int lane) {
  float rv[16]; int ri[16];
#pragma unroll
  for (int r = 0; r < 16; ++r) {
    float cv = tv[0]; int ci = ti[0];
#pragma unroll
    for (int m = 32; m >= 1; m >>= 1) {
      float ov = __shfl_xor(cv, m);
      int oi = __shfl_xor(ci, m);
      if (rank_gt(ov, oi, cv, ci)) { cv = ov; ci = oi; }
    }
    rv[r] = cv; ri[r] = ci;
    if (ti[0] == ci) {  // this lane won (key indices are globally unique)
#pragma unroll
      for (int j = 0; j < 15; ++j) { tv[j] = tv[j+1]; ti[j] = ti[j+1]; }
      tv[15] = NEG_INF; ti[15] = 0x7fffffff;
    }
  }
  if (lane == 0) {
    const float inv_scale = 0.08838834764831845f;  // 1/sqrt(128)
    float smax = rv[0];
    float ee[16]; float esum = 0.f;
#pragma unroll
    for (int j = 0; j < 16; ++j) { ee[j] = expf((rv[j] - smax) * inv_scale); esum += ee[j]; }
    float rs = 1.f / esum;
#pragma unroll
    for (int j = 0; j < 16; ++j) { attnW[off + j] = ee[j] * rs; attnI[off + j] = ri[j]; }
  }
}

// ---------- kernel 1: per-point preproc ----------
__global__ __launch_bounds__(256) void k_preproc(
    const float* __restrict__ x, const float* __restrict__ lines,
    const float* __restrict__ Wm1, const float* __restrict__ bm1,
    const float* __restrict__ Wm2, const float* __restrict__ bm2,
    float* __restrict__ pf, float* __restrict__ pe,
    float* __restrict__ slotW, int* __restrict__ plist,
    int* __restrict__ pairE, int* __restrict__ pairS, int* __restrict__ cnt)
{
  int n = blockIdx.x * 256 + threadIdx.x;
  if (n >= NPTS) return;
  float c0 = x[n*5+0], c1 = x[n*5+1], c2 = x[n*5+2];

  // ---- gating MLP ----
  float l0 = bm2[0], l1 = bm2[1], l2 = bm2[2], l3 = bm2[3];
#pragma unroll 4
  for (int j = 0; j < 64; ++j) {
    float h = fmaf(c0, Wm1[j], fmaf(c1, Wm1[64+j], fmaf(c2, Wm1[128+j], bm1[j])));
    h = fmaxf(h, 0.f);
    l0 = fmaf(h, Wm2[j*4+0], l0);
    l1 = fmaf(h, Wm2[j*4+1], l1);
    l2 = fmaf(h, Wm2[j*4+2], l2);
    l3 = fmaf(h, Wm2[j*4+3], l3);
  }
  float lg[4] = {l0, l1, l2, l3};
  float mx = fmaxf(fmaxf(l0, l1), fmaxf(l2, l3));
  float pr[4]; float ssum = 0.f;
#pragma unroll
  for (int k = 0; k < 4; ++k) { pr[k] = expf(lg[k] - mx); ssum += pr[k]; }
#pragma unroll
  for (int k = 0; k < 4; ++k) pr[k] /= ssum;
  int i0 = 0;
#pragma unroll
  for (int k = 1; k < 4; ++k) if (pr[k] > pr[i0]) i0 = k;
  int i1 = (i0 == 0) ? 1 : 0;
#pragma unroll
  for (int k = 0; k < 4; ++k) if (k != i0 && pr[k] > pr[i1]) i1 = k;
  float g0 = pr[i0], g1 = pr[i1], gs = g0 + g1;
  g0 /= gs; g1 /= gs;
  int s0 = atomicAdd(&cnt[i0], 1);
  int s1 = atomicAdd(&cnt[i1], 1);
  plist[i0*NPTS + s0] = n; slotW[i0*NPTS + s0] = g0;
  plist[i1*NPTS + s1] = n; slotW[i1*NPTS + s1] = g1;
  pairE[n*2+0] = i0; pairE[n*2+1] = i1;
  pairS[n*2+0] = s0; pairS[n*2+1] = s1;

  // ---- positional encoding (accurate sinf/cosf: args up to 512*pi) ----
  pe[(size_t)n*64 + 0] = c0;
  pe[(size_t)n*64 + 1] = c1;
  pe[(size_t)n*64 + 2] = c2;
  float cc[3] = {c0, c1, c2};
#pragma unroll
  for (int i = 0; i < 10; ++i) {
    float sc = 3.14159274101257324f * (float)(1 << i);
#pragma unroll
    for (int j = 0; j < 3; ++j) {
      float a = sc * cc[j];
      pe[(size_t)n*64 + 3 + (i*3+j)*2 + 0] = sinf(a);
      pe[(size_t)n*64 + 3 + (i*3+j)*2 + 1] = cosf(a);
    }
  }
  pe[(size_t)n*64 + 63] = 0.f;

  // ---- param feats: product of 2 line interpolations ----
  float pfv[64];
#pragma unroll
  for (int d = 0; d < 64; ++d) pfv[d] = 1.f;
  for (int i = 0; i < 2; ++i) {
    float p = x[n*5 + 3 + i] * 63.0f;
    float f = floorf(p);
    float wfr = p - f;
    int j0 = (int)f;
    int j1 = (int)fminf(f + 1.0f, 63.0f);
    const float* L = lines + (size_t)i * 64 * 64;
#pragma unroll
    for (int d = 0; d < 64; ++d) {
      float a = L[d*64 + j0];
      float b = L[d*64 + j1];
      pfv[d] *= a + wfr * (b - a);
    }
  }
#pragma unroll
  for (int d = 0; d < 64; ++d) pf[(size_t)n*64 + d] = pfv[d];
}

// ---------- kernel 2: K/V projection ----------
__global__ __launch_bounds__(256) void k_kv(
    const float* __restrict__ mem_k, const float* __restrict__ mem_v,
    const float* __restrict__ Wk, const float* __restrict__ Wv,
    float* __restrict__ Khat, float* __restrict__ Vhat)
{
  int e = blockIdx.y;
  int which = blockIdx.z;
  const float* src = which ? mem_v : mem_k;
  const float* W   = which ? Wv : Wk;
  float* dst       = which ? Vhat : Khat;
  int r0 = blockIdx.x * 32;
  __shared__ float sm[32][130];
  int tid = threadIdx.x;
  for (int idx = tid; idx < 32*32; idx += 256) {
    int r = idx >> 5, c4 = (idx & 31) * 4;
    float4 v = *(const float4*)(src + ((size_t)e*NM + r0 + r)*DD + c4);
    sm[r][c4+0] = v.x; sm[r][c4+1] = v.y; sm[r][c4+2] = v.z; sm[r][c4+3] = v.w;
  }
  __syncthreads();
  int r = tid >> 3, cb = (tid & 7) * 16;
  float acc[16];
#pragma unroll
  for (int i = 0; i < 16; ++i) acc[i] = 0.f;
  const float* We = W + (size_t)e*DD*DD;
#pragma unroll 4
  for (int k = 0; k < 128; ++k) {
    float s = sm[r][k];
    const float4* w4 = (const float4*)(We + (size_t)k*DD + cb);
#pragma unroll
    for (int q = 0; q < 4; ++q) {
      float4 wv = w4[q];
      acc[q*4+0] = fmaf(s, wv.x, acc[q*4+0]);
      acc[q*4+1] = fmaf(s, wv.y, acc[q*4+1]);
      acc[q*4+2] = fmaf(s, wv.z, acc[q*4+2]);
      acc[q*4+3] = fmaf(s, wv.w, acc[q*4+3]);
    }
  }
  float* drow = dst + ((size_t)e*NM + r0 + r)*DD + cb;
#pragma unroll
  for (int i = 0; i < 16; ++i) drow[i] = acc[i];
}

// ---------- kernel 3: routed expert SIREN MLP + LN + Q-proj ----------
__global__ __launch_bounds__(256) void k_expert(
    const float* __restrict__ pe,
    const float* __restrict__ We1, const float* __restrict__ be1,
    const float* __restrict__ We2, const float* __restrict__ be2,
    const float* __restrict__ We3, const float* __restrict__ be3,
    const float* __restrict__ ln_g, const float* __restrict__ ln_b,
    const float* __restrict__ Wq,
    const int* __restrict__ plist, const int* __restrict__ cnt,
    float* __restrict__ featsC, float* __restrict__ QC)
{
  int e = blockIdx.y;
  int count = cnt[e];
  int base = blockIdx.x * 16;
  if (base >= count) return;
  __shared__ float peT[16][68];
  __shared__ float hA[16][260];
  __shared__ float hB[16][260];
  __shared__ float fT[16][132];
  __shared__ int pts[16];
  int tid = threadIdx.x;
  if (tid < 16) {
    int slot = base + tid;
    pts[tid] = (slot < count) ? plist[e*NPTS + slot] : 0;
  }
  __syncthreads();
  for (int idx = tid; idx < 16*16; idx += 256) {
    int r = idx >> 4, c4 = (idx & 15) * 4;
    float4 v = *(const float4*)(pe + (size_t)pts[r]*64 + c4);
    peT[r][c4+0] = v.x; peT[r][c4+1] = v.y; peT[r][c4+2] = v.z; peT[r][c4+3] = v.w;
  }
  __syncthreads();

  int row = tid >> 4;
  int c16 = (tid & 15) * 16;
  int c8  = (tid & 15) * 8;

  // layer1: 63 -> 256, sin(30*)
  {
    float acc[16];
#pragma unroll
    for (int i = 0; i < 16; ++i) acc[i] = be1[e*NHE + c16 + i];
    const float* W = We1 + (size_t)e*63*NHE;
    for (int k = 0; k < 63; ++k) {
      float s = peT[row][k];
      const float4* w4 = (const float4*)(W + (size_t)k*NHE + c16);
#pragma unroll
      for (int q = 0; q < 4; ++q) {
        float4 wv = w4[q];
        acc[q*4+0] = fmaf(s, wv.x, acc[q*4+0]);
        acc[q*4+1] = fmaf(s, wv.y, acc[q*4+1]);
        acc[q*4+2] = fmaf(s, wv.z, acc[q*4+2]);
        acc[q*4+3] = fmaf(s, wv.w, acc[q*4+3]);
      }
    }
#pragma unroll
    for (int i = 0; i < 16; ++i) hA[row][c16+i] = sinf(30.0f * acc[i]);
  }
  __syncthreads();

  // layer2: 256 -> 256, sin(30*)
  {
    float acc[16];
#pragma unroll
    for (int i = 0; i < 16; ++i) acc[i] = be2[e*NHE + c16 + i];
    const float* W = We2 + (size_t)e*NHE*NHE;
#pragma unroll 2
    for (int k = 0; k < NHE; ++k) {
      float s = hA[row][k];
      const float4* w4 = (const float4*)(W + (size_t)k*NHE + c16);
#pragma unroll
      for (int q = 0; q < 4; ++q) {
        float4 wv = w4[q];
        acc[q*4+0] = fmaf(s, wv.x, acc[q*4+0]);
        acc[q*4+1] = fmaf(s, wv.y, acc[q*4+1]);
        acc[q*4+2] = fmaf(s, wv.z, acc[q*4+2]);
        acc[q*4+3] = fmaf(s, wv.w, acc[q*4+3]);
      }
    }
#pragma unroll
    for (int i = 0; i < 16; ++i) hB[row][c16+i] = sinf(30.0f * acc[i]);
  }
  __syncthreads();

  // layer3: 256 -> 128 (no activation)
  {
    float acc[8];
#pragma unroll
    for (int i = 0; i < 8; ++i) acc[i] = be3[e*DD + c8 + i];
    const float* W = We3 + (size_t)e*NHE*DD;
#pragma unroll 2
    for (int k = 0; k < NHE; ++k) {
      float s = hB[row][k];
      const float4* w4 = (const float4*)(W + (size_t)k*DD + c8);
#pragma unroll
      for (int q = 0; q < 2; ++q) {
        float4 wv = w4[q];
        acc[q*4+0] = fmaf(s, wv.x, acc[q*4+0]);
        acc[q*4+1] = fmaf(s, wv.y, acc[q*4+1]);
        acc[q*4+2] = fmaf(s, wv.z, acc[q*4+2]);
        acc[q*4+3] = fmaf(s, wv.w, acc[q*4+3]);
      }
    }
#pragma unroll
    for (int i = 0; i < 8; ++i) fT[row][c8+i] = acc[i];
  }
  __syncthreads();

  // layernorm over 128, write q into hA[row][0..127]
  {
    float sm = 0.f, sq = 0.f;
#pragma unroll
    for (int i = 0; i < 8; ++i) {
      float v = fT[row][c8 + i];
      sm += v; sq += v * v;
    }
#pragma unroll
    for (int m = 1; m < 16; m <<= 1) { sm += __shfl_xor(sm, m); sq += __shfl_xor(sq, m); }
    float mu = sm * (1.f/128.f);
    float var = sq * (1.f/128.f) - mu*mu;
    float rs = rsqrtf(var + 1e-5f);
#pragma unroll
    for (int i = 0; i < 8; ++i) {
      int ccc = c8 + i;
      hA[row][ccc] = (fT[row][ccc] - mu) * rs * ln_g[ccc] + ln_b[ccc];
    }
  }
  __syncthreads();

  // Q = q @ Wq[e]
  {
    float acc[8];
#pragma unroll
    for (int i = 0; i < 8; ++i) acc[i] = 0.f;
    const float* W = Wq + (size_t)e*DD*DD;
#pragma unroll 4
    for (int k = 0; k < DD; ++k) {
      float s = hA[row][k];
      const float4* w4 = (const float4*)(W + (size_t)k*DD + c8);
#pragma unroll
      for (int q = 0; q < 2; ++q) {
        float4 wv = w4[q];
        acc[q*4+0] = fmaf(s, wv.x, acc[q*4+0]);
        acc[q*4+1] = fmaf(s, wv.y, acc[q*4+1]);
        acc[q*4+2] = fmaf(s, wv.z, acc[q*4+2]);
        acc[q*4+3] = fmaf(s, wv.w, acc[q*4+3]);
      }
    }
    int slot = base + row;
    if (slot < count) {
      size_t o = ((size_t)e*NPTS + slot) * DD;
#pragma unroll
      for (int i = 0; i < 8; ++i) {
        featsC[o + c8 + i] = fT[row][c8 + i];
        QC[o + c8 + i] = acc[i];
      }
    }
  }
}

// ---------- kernel 4: fused scores + top-16 + attention softmax ----------
__global__ __launch_bounds__(256) void k_scores(
    const float* __restrict__ QC, const float* __restrict__ Khat,
    const int* __restrict__ cnt,
    float* __restrict__ attnW, int* __restrict__ attnI)
{
  int e = blockIdx.y;
  int count = cnt[e];
  int sbase = blockIdx.x * 8;
  if (sbase >= count) return;
  __shared__ float Ks[64][132];
  __shared__ float Qs[8][128];
  int tid = threadIdx.x;
  for (int idx = tid; idx < 8*32; idx += 256) {
    int w = idx >> 5, c4 = (idx & 31) * 4;
    int slot = sbase + w;
    float4 v = make_float4(0.f, 0.f, 0.f, 0.f);
    if (slot < count) v = *(const float4*)(QC + ((size_t)e*NPTS + slot)*DD + c4);
    Qs[w][c4+0] = v.x; Qs[w][c4+1] = v.y; Qs[w][c4+2] = v.z; Qs[w][c4+3] = v.w;
  }
  int wv = tid >> 6, lane = tid & 63;
  int sA = sbase + wv*2, sB = sA + 1;
  bool vA = sA < count, vB = sB < count;
  float tvA[16], tvB[16];
  int tiA[16], tiB[16];
#pragma unroll
  for (int i = 0; i < 16; ++i) {
    tvA[i] = NEG_INF; tiA[i] = 0x7fffffff;
    tvB[i] = NEG_INF; tiB[i] = 0x7fffffff;
  }
  for (int ch = 0; ch < NM/64; ++ch) {
    __syncthreads();
    for (int idx = tid; idx < 64*32; idx += 256) {
      int r = idx >> 5, c4 = (idx & 31) * 4;
      float4 v = *(const float4*)(Khat + ((size_t)e*NM + ch*64 + r)*DD + c4);
      Ks[r][c4+0] = v.x; Ks[r][c4+1] = v.y; Ks[r][c4+2] = v.z; Ks[r][c4+3] = v.w;
    }
    __syncthreads();
    float accA = 0.f, accB = 0.f;
    const float4* kr = (const float4*)&Ks[lane][0];
    const float4* qa = (const float4*)&Qs[wv*2][0];
    const float4* qb = (const float4*)&Qs[wv*2+1][0];
#pragma unroll
    for (int q = 0; q < 32; ++q) {
      float4 kv = kr[q];
      float4 va = qa[q];
      float4 vb = qb[q];
      accA = fmaf(kv.x, va.x, accA); accA = fmaf(kv.y, va.y, accA);
      accA = fmaf(kv.z, va.z, accA); accA = fmaf(kv.w, va.w, accA);
      accB = fmaf(kv.x, vb.x, accB); accB = fmaf(kv.y, vb.y, accB);
      accB = fmaf(kv.z, vb.z, accB); accB = fmaf(kv.w, vb.w, accB);
    }
    int key = ch*64 + lane;
    if (vA) topk_insert(tvA, tiA, accA, key);
    if (vB) topk_insert(tvB, tiB, accB, key);
  }
  if (vA) topk_merge_write(tvA, tiA, attnW, attnI, ((size_t)e*NPTS + sA)*NTK, lane);
  if (vB) topk_merge_write(tvB, tiB, attnW, attnI, ((size_t)e*NPTS + sB)*NTK, lane);
}

// ---------- kernel 5: adapter MLP + LN + attention combine ----------
__global__ __launch_bounds__(256) void k_adapter(
    const float* __restrict__ Vhat, const float* __restrict__ pf,
    const float* __restrict__ A1, const float* __restrict__ a1,
    const float* __restrict__ A2, const float* __restrict__ a2,
    const float* __restrict__ alng, const float* __restrict__ alnb,
    const float* __restrict__ attnW, const int* __restrict__ attnI,
    const float* __restrict__ featsC, const float* __restrict__ slotW,
    const int* __restrict__ plist, const int* __restrict__ cnt,
    float* __restrict__ outC)
{
  int e = blockIdx.y;
  int count = cnt[e];
  int s0 = blockIdx.x * 2;
  if (s0 >= count) return;
  __shared__ float ain[32][200];
  __shared__ float hid[32][72];
  __shared__ float accv[2][128];
  __shared__ float attw[2][16];
  __shared__ int rti[32];
  __shared__ float wsl[2];
  __shared__ int ptl[2];
  int tid = threadIdx.x;
  if (tid < 32) {
    int sl = tid >> 4, key = tid & 15;
    int slot = s0 + sl;
    if (slot < count) {
      size_t o = ((size_t)e*NPTS + slot)*NTK + key;
      rti[tid] = attnI[o];
      attw[sl][key] = attnW[o];
    } else { rti[tid] = 0; attw[sl][key] = 0.f; }
  }
  if (tid >= 32 && tid < 34) {
    int sl = tid - 32;
    int slot = s0 + sl;
    wsl[sl] = (slot < count) ? slotW[e*NPTS + slot] : 0.f;
    ptl[sl] = (slot < count) ? plist[e*NPTS + slot] : 0;
  }
  if (tid < 256) { accv[tid >> 7][tid & 127] = 0.f; }
  __syncthreads();
  // gather ain = [Vhat[ti] (128) | pf[pt] (64)]
  for (int idx = tid; idx < 32*48; idx += 256) {
    int r = idx / 48, f4 = idx - r*48;
    float4 v;
    if (f4 < 32) v = *(const float4*)(Vhat + ((size_t)e*NM + rti[r])*DD + f4*4);
    else         v = *(const float4*)(pf + (size_t)ptl[r >> 4]*64 + (f4-32)*4);
    *((float4*)&ain[r][f4*4]) = v;
  }
  __syncthreads();

  int r = tid >> 3;
  int hb = (tid & 7) * 8;
  int cb = (tid & 7) * 16;

  // hidden = relu(ain @ A1 + a1), 192 -> 64
  {
    float acc[8];
#pragma unroll
    for (int i = 0; i < 8; ++i) acc[i] = a1[e*64 + hb + i];
    const float* W = A1 + (size_t)e*192*64;
#pragma unroll 4
    for (int k = 0; k < 192; ++k) {
      float s = ain[r][k];
      const float4* w4 = (const float4*)(W + (size_t)k*64 + hb);
#pragma unroll
      for (int q = 0; q < 2; ++q) {
        float4 wv = w4[q];
        acc[q*4+0] = fmaf(s, wv.x, acc[q*4+0]);
        acc[q*4+1] = fmaf(s, wv.y, acc[q*4+1]);
        acc[q*4+2] = fmaf(s, wv.z, acc[q*4+2]);
        acc[q*4+3] = fmaf(s, wv.w, acc[q*4+3]);
      }
    }
#pragma unroll
    for (int i = 0; i < 8; ++i) hid[r][hb+i] = fmaxf(acc[i], 0.f);
  }
  __syncthreads();

  // ad = hidden @ A2 + a2, 64 -> 128; then LN; Va; weighted accumulate
  {
    float ad[16];
#pragma unroll
    for (int i = 0; i < 16; ++i) ad[i] = a2[e*DD + cb + i];
    const float* W = A2 + (size_t)e*64*DD;
#pragma unroll 4
    for (int k = 0; k < 64; ++k) {
      float s = hid[r][k];
      const float4* w4 = (const float4*)(W + (size_t)k*DD + cb);
#pragma unroll
      for (int q = 0; q < 4; ++q) {
        float4 wv = w4[q];
        ad[q*4+0] = fmaf(s, wv.x, ad[q*4+0]);
        ad[q*4+1] = fmaf(s, wv.y, ad[q*4+1]);
        ad[q*4+2] = fmaf(s, wv.z, ad[q*4+2]);
        ad[q*4+3] = fmaf(s, wv.w, ad[q*4+3]);
      }
    }
    float sm = 0.f, sq = 0.f;
#pragma unroll
    for (int i = 0; i < 16; ++i) { sm += ad[i]; sq += ad[i]*ad[i]; }
#pragma unroll
    for (int m = 1; m < 8; m <<= 1) { sm += __shfl_xor(sm, m); sq += __shfl_xor(sq, m); }
    float mu = sm * (1.f/128.f);
    float var = sq * (1.f/128.f) - mu*mu;
    float rs = rsqrtf(var + 1e-5f);
    int sl = r >> 4, key = r & 15;
    float w = attw[sl][key];
#pragma unroll
    for (int i = 0; i < 16; ++i) {
      int ccc = cb + i;
      float va = ain[r][ccc] + ((ad[i] - mu) * rs * alng[e*DD + ccc] + alnb[e*DD + ccc]);
      atomicAdd(&accv[sl][ccc], w * va);
    }
  }
  __syncthreads();
  for (int idx = tid; idx < 2*128; idx += 256) {
    int sl = idx >> 7, ccc = idx & 127;
    int slot = s0 + sl;
    if (slot < count) {
      size_t o = ((size_t)e*NPTS + slot)*DD;
      outC[o + ccc] = wsl[sl] * (accv[sl][ccc] + featsC[o + ccc]);
    }
  }
}

// ---------- kernel 6: gather pairs + final MLP + sigmoid ----------
__global__ __launch_bounds__(256) void k_final(
    const float* __restrict__ outC, const int* __restrict__ pairE, const int* __restrict__ pairS,
    const float* __restrict__ M1, const float* __restrict__ c1,
    const float* __restrict__ M2, const float* __restrict__ c2,
    const float* __restrict__ M3, const float* __restrict__ c3,
    const float* __restrict__ M4, const float* __restrict__ c4,
    float* __restrict__ out)
{
  int base = blockIdx.x * 16;
  __shared__ float sT[16][132];
  __shared__ float hA[16][264];
  __shared__ float hB[16][264];
  __shared__ int prE[32];
  __shared__ int prS[32];
  int tid = threadIdx.x;
  if (tid < 32) {
    prE[tid] = pairE[(size_t)base*2 + tid];
    prS[tid] = pairS[(size_t)base*2 + tid];
  }
  __syncthreads();
  for (int idx = tid; idx < 16*32; idx += 256) {
    int rr = idx >> 5, c4 = (idx & 31) * 4;
    float4 a = *(const float4*)(outC + ((size_t)prE[rr*2+0]*NPTS + prS[rr*2+0])*DD + c4);
    float4 b = *(const float4*)(outC + ((size_t)prE[rr*2+1]*NPTS + prS[rr*2+1])*DD + c4);
    sT[rr][c4+0] = a.x + b.x; sT[rr][c4+1] = a.y + b.y;
    sT[rr][c4+2] = a.z + b.z; sT[rr][c4+3] = a.w + b.w;
  }
  __syncthreads();

  int row = tid >> 4, c16 = (tid & 15) * 16;

  // L1: 128 -> 256 relu
  {
    float acc[16];
#pragma unroll
    for (int i = 0; i < 16; ++i) acc[i] = c1[c16 + i];
#pragma unroll 4
    for (int k = 0; k < 128; ++k) {
      float s = sT[row][k];
      const float4* w4 = (const float4*)(M1 + (size_t)k*NHM + c16);
#pragma unroll
      for (int q = 0; q < 4; ++q) {
        float4 wv = w4[q];
        acc[q*4+0] = fmaf(s, wv.x, acc[q*4+0]);
        acc[q*4+1] = fmaf(s, wv.y, acc[q*4+1]);
        acc[q*4+2] = fmaf(s, wv.z, acc[q*4+2]);
        acc[q*4+3] = fmaf(s, wv.w, acc[q*4+3]);
      }
    }
#pragma unroll
    for (int i = 0; i < 16; ++i) hA[row][c16+i] = fmaxf(acc[i], 0.f);
  }
  __syncthreads();
  // L2: 256 -> 256 relu
  {
    float acc[16];
#pragma unroll
    for (int i = 0; i < 16; ++i) acc[i] = c2[c16 + i];
#pragma unroll 2
    for (int k = 0; k < 256; ++k) {
      float s = hA[row][k];
      const float4* w4 = (const float4*)(M2 + (size_t)k*NHM + c16);
#pragma unroll
      for (int q = 0; q < 4; ++q) {
        float4 wv = w4[q];
        acc[q*4+0] = fmaf(s, wv.x, acc[q*4+0]);
        acc[q*4+1] = fmaf(s, wv.y, acc[q*4+1]);
        acc[q*4+2] = fmaf(s, wv.z, acc[q*4+2]);
        acc[q*4+3] = fmaf(s, wv.w, acc[q*4+3]);
      }
    }
#pragma unroll
    for (int i = 0; i < 16; ++i) hB[row][c16+i] = fmaxf(acc[i], 0.f);
  }
  __syncthreads();
  // L3: 256 -> 256 relu (into hA)
  {
    float acc[16];
#pragma unroll
    for (int i = 0; i < 16; ++i) acc[i] = c3[c16 + i];
#pragma unroll 2
    for (int k = 0; k < 256; ++k) {
      float s = hB[row][k];
      const float4* w4 = (const float4*)(M3 + (size_t)k*NHM + c16);
#pragma unroll
      for (int q = 0; q < 4; ++q) {
        float4 wv = w4[q];
        acc[q*4+0] = fmaf(s, wv.x, acc[q*4+0]);
        acc[q*4+1] = fmaf(s, wv.y, acc[q*4+1]);
        acc[q*4+2] = fmaf(s, wv.z, acc[q*4+2]);
        acc[q*4+3] = fmaf(s, wv.w, acc[q*4+3]);
      }
    }
#pragma unroll
    for (int i = 0; i < 16; ++i) hA[row][c16+i] = fmaxf(acc[i], 0.f);
  }
  __syncthreads();
  // final: dot(hA_row, M4) + c4 -> sigmoid
  {
    float part = 0.f;
#pragma unroll
    for (int i = 0; i < 16; ++i) part = fmaf(hA[row][c16+i], M4[c16+i], part);
#pragma unroll
    for (int m = 1; m < 16; m <<= 1) part += __shfl_xor(part, m);
    if ((tid & 15) == 0) {
      float z = part + c4[0];
      out[base + row] = 1.f / (1.f + expf(-z));
    }
  }
}

// ---------- launcher ----------
extern "C" void kernel_launch(void* const* d_in, const int* in_sizes, int n_in,
                              void* d_out, int out_size, void* d_ws, size_t ws_size,
                              hipStream_t stream)
{
  const float* x    = (const float*)d_in[0];
  const float* lines= (const float*)d_in[1];
  const float* Wm1  = (const float*)d_in[2];
  const float* bm1  = (const float*)d_in[3];
  const float* Wm2  = (const float*)d_in[4];
  const float* bm2  = (const float*)d_in[5];
  const float* We1  = (const float*)d_in[6];
  const float* be1  = (const float*)d_in[7];
  const float* We2  = (const float*)d_in[8];
  const float* be2  = (const float*)d_in[9];
  const float* We3  = (const float*)d_in[10];
  const float* be3  = (const float*)d_in[11];
  const float* ln_g = (const float*)d_in[12];
  const float* ln_b = (const float*)d_in[13];
  const float* Wq   = (const float*)d_in[14];
  const float* Wk   = (const float*)d_in[15];
  const float* Wv   = (const float*)d_in[16];
  const float* A1   = (const float*)d_in[17];
  const float* a1   = (const float*)d_in[18];
  const float* A2   = (const float*)d_in[19];
  const float* a2   = (const float*)d_in[20];
  const float* alng = (const float*)d_in[21];
  const float* alnb = (const float*)d_in[22];
  const float* mem_k= (const float*)d_in[23];
  const float* mem_v= (const float*)d_in[24];
  const float* M1   = (const float*)d_in[25];
  const float* c1   = (const float*)d_in[26];
  const float* M2   = (const float*)d_in[27];
  const float* c2   = (const float*)d_in[28];
  const float* M3   = (const float*)d_in[29];
  const float* c3   = (const float*)d_in[30];
  const float* M4   = (const float*)d_in[31];
  const float* c4   = (const float*)d_in[32];
  float* out = (float*)d_out;

  char* wp = (char*)d_ws;
  auto alloc = [&](size_t bytes) -> void* {
    void* p = (void*)wp;
    wp += (bytes + 255) & ~(size_t)255;
    return p;
  };
  float* pf     = (float*)alloc((size_t)NPTS*64*4);
  float* pe     = (float*)alloc((size_t)NPTS*64*4);
  float* Khat   = (float*)alloc((size_t)NE*NM*DD*4);
  float* Vhat   = (float*)alloc((size_t)NE*NM*DD*4);
  float* featsC = (float*)alloc((size_t)NE*NPTS*DD*4);
  float* QoutC  = (float*)alloc((size_t)NE*NPTS*DD*4);  // QC then reused as outC
  float* attnWb = (float*)alloc((size_t)NE*NPTS*NTK*4);
  float* slotW  = (float*)alloc((size_t)NE*NPTS*4);
  int*   attnIb = (int*)alloc((size_t)NE*NPTS*NTK*4);
  int*   plist  = (int*)alloc((size_t)NE*NPTS*4);
  int*   pairE  = (int*)alloc((size_t)NPTS*2*4);
  int*   pairS  = (int*)alloc((size_t)NPTS*2*4);
  int*   cnt    = (int*)alloc(64);

  hipMemsetAsync(cnt, 0, 64, stream);
  k_preproc<<<NPTS/256, 256, 0, stream>>>(x, lines, Wm1, bm1, Wm2, bm2,
                                          pf, pe, slotW, plist, pairE, pairS, cnt);
  k_kv<<<dim3(NM/32, NE, 2), 256, 0, stream>>>(mem_k, mem_v, Wk, Wv, Khat, Vhat);
  k_expert<<<dim3(NPTS/16, NE), 256, 0, stream>>>(pe, We1, be1, We2, be2, We3, be3,
                                                  ln_g, ln_b, Wq, plist, cnt, featsC, QoutC);
  k_scores<<<dim3(NPTS/8, NE), 256, 0, stream>>>(QoutC, Khat, cnt, attnWb, attnIb);
  k_adapter<<<dim3(NPTS/2, NE), 256, 0, stream>>>(Vhat, pf, A1, a1, A2, a2, alng, alnb,
                                                  attnWb, attnIb, featsC, slotW, plist, cnt,
                                                  QoutC);
  k_final<<<NPTS/16, 256, 0, stream>>>(QoutC, pairE, pairS, M1, c1, M2, c2, M3, c3, M4, c4, out);
}